// Round 5
// baseline (44.357 us; speedup 1.0000x reference)
//
#include <hip/hip_runtime.h>

typedef float v2f __attribute__((ext_vector_type(2)));

#define IMG_H 384
#define IMG_W 512
#define RPT 6           // output rows per thread
#define TY  4           // thread strips per block (y)
#define NLX 128         // threads across x (128 * 4 cols = 512 = full width)

struct RowH {
    v2f hx[4];     // (sum3_p, sum3_t) horizontal 3-tap for 4 outputs
    v2f hxx[4];    // (sum3_pp, sum3_tt)
    float hpt[4];  // sum3_pt
};

__device__ __forceinline__ void compute_row(
    const float* __restrict__ pred, const float* __restrict__ target,
    size_t base, int ry, int col0, int gxl, int gxr, RowH& h)
{
    int gy = ry;
    if (gy < 0) gy = -gy;
    else if (gy >= IMG_H) gy = 2 * IMG_H - 2 - gy;
    const float* rp = pred   + base + (size_t)gy * IMG_W;
    const float* rt = target + base + (size_t)gy * IMG_W;

    float4 p4 = *(const float4*)(rp + col0);
    float4 t4 = *(const float4*)(rt + col0);
    float pl = rp[gxl], pr = rp[gxr];
    float tl = rt[gxl], tr = rt[gxr];

    v2f x0 = {pl,   tl};
    v2f x1 = {p4.x, t4.x};
    v2f x2 = {p4.y, t4.y};
    v2f x3 = {p4.z, t4.z};
    v2f x4 = {p4.w, t4.w};
    v2f x5 = {pr,   tr};

    // horizontal 3-tap sums of (p,t), shared partials
    v2f a = x1 + x2, b = x3 + x4;
    h.hx[0] = x0 + a;  h.hx[1] = a + x3;
    h.hx[2] = x2 + b;  h.hx[3] = b + x5;

    // (pp,tt) packed squares
    v2f q0 = x0*x0, q1 = x1*x1, q2 = x2*x2, q3 = x3*x3, q4 = x4*x4, q5 = x5*x5;
    v2f aq = q1 + q2, bq = q3 + q4;
    h.hxx[0] = q0 + aq;  h.hxx[1] = aq + q3;
    h.hxx[2] = q2 + bq;  h.hxx[3] = bq + q5;

    // pt scalar chain
    float m0 = x0.x*x0.y, m1 = x1.x*x1.y, m2 = x2.x*x2.y,
          m3 = x3.x*x3.y, m4 = x4.x*x4.y, m5 = x5.x*x5.y;
    float am = m1 + m2, bm = m3 + m4;
    h.hpt[0] = m0 + am;  h.hpt[1] = am + m3;
    h.hpt[2] = m2 + bm;  h.hpt[3] = bm + m5;
}

__device__ __forceinline__ void emit_row(
    float* __restrict__ out, size_t base, int row, int col0,
    const RowH& A, const RowH& B, const RowH& C)
{
    const float C1 = 1e-4f;    // 0.01^2
    const float C2 = 9e-4f;    // 0.03^2
    const float inv9 = 1.0f / 9.0f;

    float rv[4];
    #pragma unroll
    for (int j = 0; j < 4; ++j) {
        v2f sx  = A.hx[j]  + B.hx[j]  + C.hx[j];    // (s_p, s_t)
        v2f sxx = A.hxx[j] + B.hxx[j] + C.hxx[j];   // (s_pp, s_tt)
        float spt = A.hpt[j] + B.hpt[j] + C.hpt[j];

        v2f u  = sx * inv9;                          // (up, ut)
        v2f uu = u * u;                              // (up^2, ut^2)
        v2f sig = sxx * inv9 - uu;                   // (sig_p, sig_t)
        float upt   = u.x * u.y;
        float sigco = fmaf(spt, inv9, -upt);

        float num = fmaf(2.f, upt, C1) * fmaf(2.f, sigco, C2);
        float den = (uu.x + uu.y + C1) * (sig.x + sig.y + C2);
        float q = num * __builtin_amdgcn_rcpf(den);
        rv[j] = fminf(fmaxf(fmaf(q, -0.5f, 0.5f), 0.f), 1.f);
    }
    float4 res = make_float4(rv[0], rv[1], rv[2], rv[3]);
    *(float4*)(out + base + (size_t)row * IMG_W + col0) = res;
}

__global__ __launch_bounds__(NLX * TY) void ssim_kernel(
    const float* __restrict__ pred,
    const float* __restrict__ target,
    float* __restrict__ out)
{
    const int lx   = threadIdx.x;            // 0..127
    const int col0 = 4 * lx;
    const size_t base = (size_t)blockIdx.z * (IMG_H * IMG_W);
    const int y0 = (blockIdx.y * TY + threadIdx.y) * RPT;

    const int gxl = col0 ? col0 - 1 : 1;                       // reflect x=-1 -> 1
    const int gxr = (col0 + 4 < IMG_W) ? col0 + 4 : IMG_W - 2; // reflect x=W -> W-2

    RowH A, B, Cc;
    compute_row(pred, target, base, y0 - 1, col0, gxl, gxr, A);
    compute_row(pred, target, base, y0,     col0, gxl, gxr, B);

    #pragma unroll
    for (int r3 = 0; r3 < RPT; r3 += 3) {
        compute_row(pred, target, base, y0 + r3 + 1, col0, gxl, gxr, Cc);
        emit_row(out, base, y0 + r3,     col0, A, B, Cc);
        compute_row(pred, target, base, y0 + r3 + 2, col0, gxl, gxr, A);
        emit_row(out, base, y0 + r3 + 1, col0, B, Cc, A);
        compute_row(pred, target, base, y0 + r3 + 3, col0, gxl, gxr, B);
        emit_row(out, base, y0 + r3 + 2, col0, Cc, A, B);
    }
}

extern "C" void kernel_launch(void* const* d_in, const int* in_sizes, int n_in,
                              void* d_out, int out_size, void* d_ws, size_t ws_size,
                              hipStream_t stream) {
    const float* pred   = (const float*)d_in[0];
    const float* target = (const float*)d_in[1];
    float* out = (float*)d_out;

    const int planes = in_sizes[0] / (IMG_H * IMG_W);   // 32*3 = 96

    dim3 block(NLX, TY);                                 // 512 threads
    dim3 grid(1, IMG_H / (TY * RPT), planes);            // (1, 16, 96)
    ssim_kernel<<<grid, block, 0, stream>>>(pred, target, out);
}